// Round 6
// baseline (355.256 us; speedup 1.0000x reference)
//
#include <hip/hip_runtime.h>

#define NT 256

typedef __attribute__((ext_vector_type(8))) short short8b;
typedef __attribute__((ext_vector_type(4))) float f32x4;

__device__ inline unsigned short f2bf(float f) {
    unsigned u = __float_as_uint(f);
    unsigned r = (u + 0x7fffu + ((u >> 16) & 1u)) >> 16;
    return (unsigned short)r;
}
__device__ inline float bf2f(unsigned short h) {
    return __uint_as_float(((unsigned)h) << 16);
}

// ---------------- workspace layout (float offsets) ----------------
// [0..8192) floats repurposed: spw_hi u16[8192] then spw_lo u16[8192], layout [h][c]
#define WS_SC1     8192     // [128] bn1 scale
#define WS_SH1     8320     // [128] bn1 shift (conv_b folded)
#define WS_SC2     8448     // [128] bn2 scale
#define WS_SH2     8576     // [128] bn2 shift
#define WS_LIWT    8704     // [128][64]  li_wT[j][o] = li_w[o][j]
#define WS_TW1T    16896    // [150][64]  tda_w1T[i][o]
#define WS_TW2T    26496    // [64][32]   tda_w2T[j][o2]
#define WS_CW1T    28544    // [672][128] cls_w1T[j][c]
#define WS_TOTAL   114560   // end of transposed tables
#define WS_WG      114560   // [10] Wg window constants
#define WS_WBASE   114688   // [B][10][128] window features (persistent)
#define WS_CURBASE (114688 + 2048*1280)   // cur region (reused per group)
#define CUR_STRIDE 20480    // 64*320 floats per b

// ---------------- prep: transposes + BN folds + Wg + sp_w bf16 hi/lo ----------------
__global__ void prep_kernel(
    const float* __restrict__ conv_b, const float* __restrict__ bn1_g,
    const float* __restrict__ bn1_b,  const float* __restrict__ bn1_m,
    const float* __restrict__ bn1_v,  const float* __restrict__ sp_w,
    const float* __restrict__ li_w,   const float* __restrict__ tda_w1,
    const float* __restrict__ tda_w2, const float* __restrict__ cls_w1,
    const float* __restrict__ bn2_g,  const float* __restrict__ bn2_b,
    const float* __restrict__ bn2_m,  const float* __restrict__ bn2_v,
    float* __restrict__ ws)
{
    int i = blockIdx.x * NT + threadIdx.x;
    if (i > WS_TOTAL) return;
    if (i == WS_TOTAL) {                    // Wg[10]: data-independent li-bias windows
        float g = 0.f, sE = 0.f, sL = 0.f; int w = 0;
        for (int t = 0; t < 320; ++t) {
            g = fmaf(0.9f, g, 1.f);
            int pos = t & 31;
            if (pos < 16) sE += g; else sL += g;
            if (pos == 31) { ws[WS_WG + w] = sL - sE; ++w; sE = 0.f; sL = 0.f; }
        }
        return;
    }
    if (i < 8192) {                         // sp_w bf16 hi/lo split ([h][c] natural layout)
        unsigned short* ws16 = (unsigned short*)ws;
        float v = sp_w[i];
        unsigned short hv = f2bf(v);
        ws16[i] = hv;
        ws16[8192 + i] = f2bf(v - bf2f(hv));
    } else if (i < WS_SC1) {                // gap (unused)
    } else if (i < WS_SH1) {                // bn1 scale
        int c = i - WS_SC1;
        float vv = bn1_v[c] + 1e-5f;
        ws[i] = (float)((double)bn1_g[c] / sqrt((double)vv));
    } else if (i < WS_SC2) {                // bn1 shift
        int c = i - WS_SH1;
        float vv = bn1_v[c] + 1e-5f;
        double s = (double)bn1_g[c] / sqrt((double)vv);
        ws[i] = (float)(((double)conv_b[c] - (double)bn1_m[c])*s + (double)bn1_b[c]);
    } else if (i < WS_SH2) {                // bn2 scale
        int c = i - WS_SC2;
        float vv = bn2_v[c] + 1e-5f;
        ws[i] = (float)((double)bn2_g[c] / sqrt((double)vv));
    } else if (i < WS_LIWT) {               // bn2 shift
        int c = i - WS_SH2;
        float vv = bn2_v[c] + 1e-5f;
        double s = (double)bn2_g[c] / sqrt((double)vv);
        ws[i] = (float)((double)bn2_b[c] - (double)bn2_m[c]*s);
    } else if (i < WS_TW1T) {               // li_wT
        int t = i - WS_LIWT; int j = t >> 6, o = t & 63;
        ws[i] = li_w[o*128 + j];
    } else if (i < WS_TW2T) {               // tda_w1T
        int t = i - WS_TW1T; int r = t >> 6, o = t & 63;
        ws[i] = tda_w1[o*150 + r];
    } else if (i < WS_CW1T) {               // tda_w2T
        int t = i - WS_TW2T; int j = t >> 5, o = t & 31;
        ws[i] = tda_w2[o*64 + j];
    } else {                                // cls_w1T
        int t = i - WS_CW1T; int j = t >> 7, c = t & 127;
        ws[i] = cls_w1[c*672 + j];
    }
}

// ---------------- kernel A: barrier-free conv + BN + ReLU + bf16x4 MFMA proj ----
// one block per (b, 64-t chunk); each WAVE owns a 16-t slice end-to-end.
// writes cur[bi][h][t] (group-local bi)
__launch_bounds__(NT, 4)
__global__ void convproj_kernel(
    const float* __restrict__ x, const float* __restrict__ conv_w,
    const float* __restrict__ ws, float* __restrict__ cur, int b0)
{
    __shared__ unsigned short ylds[2][64*128];   // [plane][t][c] swizzled, 32 KB

    const int tid = threadIdx.x;
    const int bi  = blockIdx.x / 5;
    const int chk = blockIdx.x % 5;
    const int w   = tid >> 6;          // wave -> 16-t slice
    const int l   = tid & 63;
    const int ts0 = chk*64 + w*16;     // global t base of this wave's slice
    const int ic  = l;                 // input channel (64 channels, 1/lane)

    // ---- per-lane x window: 30 rows of channel ic (coalesced 256B/instr) ----
    const float* xb = x + (size_t)(b0 + bi) * 20480 + ic;
    float xr[30];
    #pragma unroll
    for (int r = 0; r < 30; ++r) {
        int t = ts0 - 7 + r;
        xr[r] = ((unsigned)t < 320u) ? xb[(size_t)t * 64] : 0.f;
    }
    // weights for the two output channels fed by ic
    float w0[15], w1[15];
    #pragma unroll
    for (int k = 0; k < 15; ++k) {
        w0[k] = conv_w[(2*ic)*15 + k];
        w1[k] = conv_w[(2*ic + 1)*15 + k];
    }
    const float sA = ws[WS_SC1 + 2*ic],     hA = ws[WS_SH1 + 2*ic];
    const float sB = ws[WS_SC1 + 2*ic + 1], hB = ws[WS_SH1 + 2*ic + 1];

    // ---- conv + BN + ReLU + hi/lo split -> own LDS slice (wave-local) ----
    unsigned short* yh = &ylds[0][0];
    unsigned short* yl = &ylds[1][0];
    #pragma unroll
    for (int j = 0; j < 16; ++j) {
        float a0 = 0.f, a1 = 0.f;
        #pragma unroll
        for (int k = 0; k < 15; ++k) {
            a0 = fmaf(xr[j + k], w0[k], a0);
            a1 = fmaf(xr[j + k], w1[k], a1);
        }
        float y0 = fmaxf(fmaf(a0, sA, hA), 0.f);
        float y1 = fmaxf(fmaf(a1, sB, hB), 0.f);
        int tt = w*16 + j;             // row within block tile [0,64)
        unsigned off = (unsigned)(tt*256) + (((unsigned)(ic*4)) ^ ((unsigned)((tt & 7) << 4)));
        unsigned short y0h = f2bf(y0), y1h = f2bf(y1);
        unsigned short y0l = f2bf(y0 - bf2f(y0h)), y1l = f2bf(y1 - bf2f(y1h));
        *(unsigned*)((char*)yh + off) = (unsigned)y0h | ((unsigned)y1h << 16);
        *(unsigned*)((char*)yl + off) = (unsigned)y0l | ((unsigned)y1l << 16);
    }
    // wave-local LDS RAW: same-wave DS ops are ordered; drain writes, pin order.
    asm volatile("s_waitcnt lgkmcnt(0)" ::: "memory");
    __builtin_amdgcn_sched_barrier(0);

    // ---- MFMA: wave computes cur[all 64 h][its 16 t], bf16x4 ----
    {
        const int tl = w*16 + (l & 15);    // row in block tile (local t)
        const int kg = l >> 4;             // k quarter-group
        short8b Bh[4], Bl[4];
        const unsigned tswz = (unsigned)((tl & 7) << 4);
        #pragma unroll
        for (int ks = 0; ks < 4; ++ks) {
            unsigned off = (unsigned)(tl*256) + (((unsigned)(ks*64 + kg*16)) ^ tswz);
            Bh[ks] = *(const short8b*)((const char*)yh + off);
            Bl[ks] = *(const short8b*)((const char*)yl + off);
        }

        const unsigned short* wsh = (const unsigned short*)ws;  // spw_hi [64][128]
        const unsigned short* wsl = wsh + 8192;                 // spw_lo
        const int ha = l & 15;
        float* cb0 = cur + (size_t)bi * CUR_STRIDE + (size_t)(kg*4)*320 + chk*64 + tl;

        #pragma unroll
        for (int mt = 0; mt < 4; ++mt) {
            const unsigned short* ap = wsh + (mt*16 + ha)*128;
            const unsigned short* lp = wsl + (mt*16 + ha)*128;
            f32x4 acc = {0.f, 0.f, 0.f, 0.f};
            #pragma unroll
            for (int ks = 0; ks < 4; ++ks) {
                short8b Ah = *(const short8b*)(ap + ks*32 + kg*8);
                short8b Al = *(const short8b*)(lp + ks*32 + kg*8);
                acc = __builtin_amdgcn_mfma_f32_16x16x32_bf16(Ah, Bh[ks], acc, 0, 0, 0);
                acc = __builtin_amdgcn_mfma_f32_16x16x32_bf16(Ah, Bl[ks], acc, 0, 0, 0);
                acc = __builtin_amdgcn_mfma_f32_16x16x32_bf16(Al, Bh[ks], acc, 0, 0, 0);
                acc = __builtin_amdgcn_mfma_f32_16x16x32_bf16(Al, Bl[ks], acc, 0, 0, 0);
            }
            // D: row (h) = mt*16 + kg*4 + r, col (t) = tl
            float* cb = cb0 + (size_t)(mt*16)*320;
            #pragma unroll
            for (int r = 0; r < 4; ++r)
                cb[(size_t)r*320] = acc[r];
        }
    }
}

// ---------------- kernel B: LIF scan, one wave per batch element ----------------
__device__ __forceinline__ void lif16(float4 n0, float4 n1, float4 n2, float4 n3,
    float spb, float& mf, float& ms, float& rlo, float& rhi,
    float& slo, float& shi)
{
    float v[16] = {n0.x,n0.y,n0.z,n0.w, n1.x,n1.y,n1.z,n1.w,
                   n2.x,n2.y,n2.z,n2.w, n3.x,n3.y,n3.z,n3.w};
    slo = 0.f; shi = 0.f;
    #pragma unroll
    for (int q = 0; q < 16; ++q) {
        float c = v[q] + spb;
        mf = fmaf(0.5f, mf, c);
        bool sf = (mf - 0.5f) >= 0.f;
        ms = fmaf(0.9f, ms, c);
        bool ss = (ms - 1.0f) >= 0.f;
        mf = sf ? 0.f : mf;
        ms = ss ? 0.f : ms;
        rlo = fmaf(0.9f, rlo, sf ? 1.f : 0.f);
        rhi = fmaf(0.9f, rhi, ss ? 1.f : 0.f);
        slo += rlo; shi += rhi;
    }
}

__global__ void scan_kernel(const float* __restrict__ cur,
                            const float* __restrict__ sp_b,
                            float* __restrict__ W, int b0, int nb)
{
    const int wv = (int)((blockIdx.x * (unsigned)blockDim.x + threadIdx.x) >> 6);
    if (wv >= nb) return;
    const int lane = threadIdx.x & 63;
    const float* cb = cur + (size_t)wv * CUR_STRIDE + (size_t)lane * 320;
    const float spb = sp_b[lane];
    float* Wb = W + (size_t)(b0 + wv) * 1280;

    float mf = 0.f, ms = 0.f, rlo = 0.f, rhi = 0.f;

    // double-buffered prefetch, 2 tiles (128B/lane) in flight
    float4 A0 = *reinterpret_cast<const float4*>(cb);
    float4 A1 = *reinterpret_cast<const float4*>(cb + 4);
    float4 A2 = *reinterpret_cast<const float4*>(cb + 8);
    float4 A3 = *reinterpret_cast<const float4*>(cb + 12);
    float4 B0 = *reinterpret_cast<const float4*>(cb + 16);
    float4 B1 = *reinterpret_cast<const float4*>(cb + 20);
    float4 B2 = *reinterpret_cast<const float4*>(cb + 24);
    float4 B3 = *reinterpret_cast<const float4*>(cb + 28);

    #pragma unroll 1
    for (int tb = 0; tb < 20; tb += 2) {
        float sE_lo, sE_hi, slo, shi;
        lif16(A0, A1, A2, A3, spb, mf, ms, rlo, rhi, sE_lo, sE_hi);
        if (tb + 2 < 20) {
            const float* p = cb + (tb + 2) * 16;
            A0 = *reinterpret_cast<const float4*>(p);
            A1 = *reinterpret_cast<const float4*>(p + 4);
            A2 = *reinterpret_cast<const float4*>(p + 8);
            A3 = *reinterpret_cast<const float4*>(p + 12);
        }
        lif16(B0, B1, B2, B3, spb, mf, ms, rlo, rhi, slo, shi);
        if (tb + 3 < 20) {
            const float* p = cb + (tb + 3) * 16;
            B0 = *reinterpret_cast<const float4*>(p);
            B1 = *reinterpret_cast<const float4*>(p + 4);
            B2 = *reinterpret_cast<const float4*>(p + 8);
            B3 = *reinterpret_cast<const float4*>(p + 12);
        }
        int wdx = tb >> 1;
        Wb[wdx*128 + lane]      = slo - sE_lo;
        Wb[wdx*128 + 64 + lane] = shi - sE_hi;
    }
}

// ---------------- kernel C: classifier epilogue, 4 b per block ----------------
__global__ void epilogue_kernel(
    const float* __restrict__ tda,    const float* __restrict__ li_b,
    const float* __restrict__ tda_b1, const float* __restrict__ tda_b2,
    const float* __restrict__ cls_b1, const float* __restrict__ cls_w2,
    const float* __restrict__ cls_b2, const float* __restrict__ ws,
    const float* __restrict__ W,      float* __restrict__ out, int B)
{
    __shared__ float Wl[4*1280];
    __shared__ float t1[4][64], tf[4][32], dp[4][640], h1[4][128];
    const int b0b = blockIdx.x * 4, tid = threadIdx.x;
    const int nvalid = (B - b0b < 4) ? (B - b0b) : 4;

    for (int i = tid; i < nvalid*1280; i += NT)
        Wl[i] = W[(size_t)b0b*1280 + i];
    __syncthreads();

    const float* __restrict__ liwT = ws + WS_LIWT;
    const float* __restrict__ tw1T = ws + WS_TW1T;
    const float* __restrict__ tw2T = ws + WS_TW2T;
    const float* __restrict__ cw1T = ws + WS_CW1T;

    {   // tda layer 1: 4b x 64o = 256 threads
        int bb = tid >> 6, o = tid & 63;
        if (bb < nvalid) {
            const float* tdab = tda + (size_t)(b0b + bb)*150;
            float acc = tda_b1[o];
            for (int i2 = 0; i2 < 150; ++i2)
                acc = fmaf(tdab[i2], tw1T[i2*64 + o], acc);
            t1[bb][o] = fmaxf(acc, 0.f);
        }
    }
    __syncthreads();
    if (tid < 128) {                    // tda layer 2: 4b x 32o
        int bb = tid >> 5, o = tid & 31;
        if (bb < nvalid) {
            float acc = tda_b2[o];
            #pragma unroll 8
            for (int j = 0; j < 64; ++j)
                acc = fmaf(t1[bb][j], tw2T[j*32 + o], acc);
            tf[bb][o] = fmaxf(acc, 0.f);
        }
    }
    {   // dp_feat = (1/16) * (li_w @ W + li_b * Wg): 4b x 64o, 10 w each
        int bb = tid >> 6, o = tid & 63;
        if (bb < nvalid) {
            float lb = li_b[o];
            for (int w = 0; w < 10; ++w) {
                float acc = lb * ws[WS_WG + w];
                const float* Wr = &Wl[bb*1280 + w*128];
                #pragma unroll 4
                for (int j = 0; j < 128; ++j)
                    acc = fmaf(Wr[j], liwT[j*64 + o], acc);
                dp[bb][w*64 + o] = 0.0625f * acc;
            }
        }
    }
    __syncthreads();
    {   // classifier layer 1 + BN2 + ReLU: 4b x 128c = 512 outputs
        #pragma unroll
        for (int rep = 0; rep < 2; ++rep) {
            int idx = rep*NT + tid;
            int bb = idx >> 7, c = idx & 127;
            if (bb < nvalid) {
                float acc = cls_b1[c];
                for (int j = 0; j < 640; ++j)
                    acc = fmaf(dp[bb][j], cw1T[j*128 + c], acc);
                #pragma unroll 4
                for (int j = 0; j < 32; ++j)
                    acc = fmaf(tf[bb][j], cw1T[(640 + j)*128 + c], acc);
                float s2 = ws[WS_SC2 + c], sh2 = ws[WS_SH2 + c];
                h1[bb][c] = fmaxf(fmaf(acc, s2, sh2), 0.f);
            }
        }
    }
    __syncthreads();
    if (tid < 16) {                     // classifier layer 2: 4b x 4o
        int bb = tid >> 2, o = tid & 3;
        if (bb < nvalid) {
            float acc = cls_b2[o];
            for (int c = 0; c < 128; ++c)
                acc = fmaf(h1[bb][c], cls_w2[o*128 + c], acc);
            out[(size_t)(b0b + bb)*4 + o] = acc;
        }
    }
}

extern "C" void kernel_launch(void* const* d_in, const int* in_sizes, int n_in,
                              void* d_out, int out_size, void* d_ws, size_t ws_size,
                              hipStream_t stream) {
    const float* x      = (const float*)d_in[0];
    const float* tda    = (const float*)d_in[1];
    const float* conv_w = (const float*)d_in[2];
    const float* conv_b = (const float*)d_in[3];
    const float* bn1_g  = (const float*)d_in[4];
    const float* bn1_b  = (const float*)d_in[5];
    const float* bn1_m  = (const float*)d_in[6];
    const float* bn1_v  = (const float*)d_in[7];
    const float* sp_w   = (const float*)d_in[8];
    const float* sp_b   = (const float*)d_in[9];
    const float* li_w   = (const float*)d_in[10];
    const float* li_b   = (const float*)d_in[11];
    const float* tda_w1 = (const float*)d_in[12];
    const float* tda_b1 = (const float*)d_in[13];
    const float* tda_w2 = (const float*)d_in[14];
    const float* tda_b2 = (const float*)d_in[15];
    const float* cls_w1 = (const float*)d_in[16];
    const float* cls_b1 = (const float*)d_in[17];
    const float* bn2_g  = (const float*)d_in[18];
    const float* bn2_b  = (const float*)d_in[19];
    const float* bn2_m  = (const float*)d_in[20];
    const float* bn2_v  = (const float*)d_in[21];
    const float* cls_w2 = (const float*)d_in[22];
    const float* cls_b2 = (const float*)d_in[23];
    float* ws  = (float*)d_ws;
    float* out = (float*)d_out;

    const int B = in_sizes[0] / (320 * 64);   // 2048

    prep_kernel<<<(WS_TOTAL + 1 + NT - 1)/NT, NT, 0, stream>>>(
        conv_b, bn1_g, bn1_b, bn1_m, bn1_v, sp_w,
        li_w, tda_w1, tda_w2, cls_w1,
        bn2_g, bn2_b, bn2_m, bn2_v, ws);

    // batch grouping to fit cur region into ws
    long cap = (long)(ws_size / 4) - (long)WS_CURBASE;
    int nbg = (int)(cap / CUR_STRIDE);
    if (nbg < 1) nbg = 1;
    if (nbg > B) nbg = B;

    for (int g0 = 0; g0 < B; g0 += nbg) {
        int nb = (B - g0 < nbg) ? (B - g0) : nbg;
        convproj_kernel<<<nb*5, NT, 0, stream>>>(
            x, conv_w, ws, ws + WS_CURBASE, g0);
        scan_kernel<<<(nb + 3)/4, NT, 0, stream>>>(
            ws + WS_CURBASE, sp_b, ws + WS_WBASE, g0, nb);
    }

    epilogue_kernel<<<(B + 3)/4, NT, 0, stream>>>(
        tda, li_b, tda_b1, tda_b2, cls_b1, cls_w2, cls_b2,
        ws, ws + WS_WBASE, out, B);
}

// Round 7
// 335.956 us; speedup vs baseline: 1.0574x; 1.0574x over previous
//
#include <hip/hip_runtime.h>

#define NT  256
#define FNT 320

typedef __attribute__((ext_vector_type(8))) short short8b;
typedef __attribute__((ext_vector_type(4))) float f32x4;

__device__ inline unsigned short f2bf(float f) {
    unsigned u = __float_as_uint(f);
    unsigned r = (u + 0x7fffu + ((u >> 16) & 1u)) >> 16;
    return (unsigned short)r;
}
__device__ inline float bf2f(unsigned short h) {
    return __uint_as_float(((unsigned)h) << 16);
}

// ---------------- workspace layout (float offsets) ----------------
// [0..8192) floats repurposed: spw_hi u16[8192] then spw_lo u16[8192], layout [h][c]
#define WS_SC1     8192     // [128] bn1 scale
#define WS_SH1     8320     // [128] bn1 shift (conv_b folded)
#define WS_SC2     8448     // [128] bn2 scale
#define WS_SH2     8576     // [128] bn2 shift
#define WS_LIWT    8704     // [128][64]  li_wT[j][o] = li_w[o][j]
#define WS_TW1T    16896    // [150][64]  tda_w1T[i][o]
#define WS_TW2T    26496    // [64][32]   tda_w2T[j][o2]
#define WS_CW1T    28544    // [672][128] cls_w1T[j][c]
#define WS_TOTAL   114560   // end of transposed tables
#define WS_WG      114560   // [10] Wg window constants
#define WS_WBASE   114688   // [B][10][128] window features

// ---------------- prep: transposes + BN folds + Wg + sp_w bf16 hi/lo ----------------
__global__ void prep_kernel(
    const float* __restrict__ conv_b, const float* __restrict__ bn1_g,
    const float* __restrict__ bn1_b,  const float* __restrict__ bn1_m,
    const float* __restrict__ bn1_v,  const float* __restrict__ sp_w,
    const float* __restrict__ li_w,   const float* __restrict__ tda_w1,
    const float* __restrict__ tda_w2, const float* __restrict__ cls_w1,
    const float* __restrict__ bn2_g,  const float* __restrict__ bn2_b,
    const float* __restrict__ bn2_m,  const float* __restrict__ bn2_v,
    float* __restrict__ ws)
{
    int i = blockIdx.x * NT + threadIdx.x;
    if (i > WS_TOTAL) return;
    if (i == WS_TOTAL) {                    // Wg[10]: data-independent li-bias windows
        float g = 0.f, sE = 0.f, sL = 0.f; int w = 0;
        for (int t = 0; t < 320; ++t) {
            g = fmaf(0.9f, g, 1.f);
            int pos = t & 31;
            if (pos < 16) sE += g; else sL += g;
            if (pos == 31) { ws[WS_WG + w] = sL - sE; ++w; sE = 0.f; sL = 0.f; }
        }
        return;
    }
    if (i < 8192) {                         // sp_w bf16 hi/lo split ([h][c] natural layout)
        unsigned short* ws16 = (unsigned short*)ws;
        float v = sp_w[i];
        unsigned short hv = f2bf(v);
        ws16[i] = hv;
        ws16[8192 + i] = f2bf(v - bf2f(hv));
    } else if (i < WS_SC1) {                // gap (unused)
    } else if (i < WS_SH1) {                // bn1 scale
        int c = i - WS_SC1;
        float vv = bn1_v[c] + 1e-5f;
        ws[i] = (float)((double)bn1_g[c] / sqrt((double)vv));
    } else if (i < WS_SC2) {                // bn1 shift
        int c = i - WS_SH1;
        float vv = bn1_v[c] + 1e-5f;
        double s = (double)bn1_g[c] / sqrt((double)vv);
        ws[i] = (float)(((double)conv_b[c] - (double)bn1_m[c])*s + (double)bn1_b[c]);
    } else if (i < WS_SH2) {                // bn2 scale
        int c = i - WS_SC2;
        float vv = bn2_v[c] + 1e-5f;
        ws[i] = (float)((double)bn2_g[c] / sqrt((double)vv));
    } else if (i < WS_LIWT) {               // bn2 shift
        int c = i - WS_SH2;
        float vv = bn2_v[c] + 1e-5f;
        double s = (double)bn2_g[c] / sqrt((double)vv);
        ws[i] = (float)((double)bn2_b[c] - (double)bn2_m[c]*s);
    } else if (i < WS_TW1T) {               // li_wT
        int t = i - WS_LIWT; int j = t >> 6, o = t & 63;
        ws[i] = li_w[o*128 + j];
    } else if (i < WS_TW2T) {               // tda_w1T
        int t = i - WS_TW1T; int r = t >> 6, o = t & 63;
        ws[i] = tda_w1[o*150 + r];
    } else if (i < WS_CW1T) {               // tda_w2T
        int t = i - WS_TW2T; int j = t >> 5, o = t & 31;
        ws[i] = tda_w2[o*64 + j];
    } else {                                // cls_w1T
        int t = i - WS_CW1T; int j = t >> 7, c = t & 127;
        ws[i] = cls_w1[c*672 + j];
    }
}

// cur LDS swizzle: bank-free for both MFMA store (lanes = t×kg) and scan read (lanes = h)
__device__ __forceinline__ int cidx(int t, int h) {
    return t*64 + (h ^ ((t & 3) | (((t >> 2) & 1) << 4)));
}

// ---------------- fused kernel: one block per b -----------------------------
// waves 0-3: conv + BN + ReLU + bf16x4 MFMA proj -> cur LDS (double-buffered)
// wave 4:    LIF scan of previous chunk -> W features to ws
__launch_bounds__(FNT, 2)
__global__ void fused_kernel(
    const float* __restrict__ x, const float* __restrict__ conv_w,
    const float* __restrict__ sp_b, const float* __restrict__ ws,
    float* __restrict__ wfeat)
{
    __shared__ unsigned short ylds[2][64*128];   // hi/lo planes, swizzled, 32 KB
    __shared__ float curl[2][64*64];             // double-buffered cur, swizzled, 32 KB

    const int tid = threadIdx.x;
    const int b   = blockIdx.x;
    const int wid = tid >> 6;
    const int l   = tid & 63;

    // ---- producer state ----
    const int w  = wid;            // wave -> 16-t slice (waves 0-3)
    const int ic = l;
    const float* xb = x + (size_t)b * 20480 + ic;
    float w0[15], w1[15];
    float sA = 0.f, hA = 0.f, sB = 0.f, hB = 0.f;
    float xr0[30], xr1[30];
    const unsigned short* wsh = (const unsigned short*)ws;  // spw_hi [64][128]
    const unsigned short* wsl = wsh + 8192;                 // spw_lo

    // ---- scanner state ----
    float spb = 0.f;
    float mf = 0.f, ms = 0.f, rlo = 0.f, rhi = 0.f;
    float* Wb = wfeat + (size_t)b * 1280;

    if (wid < 4) {
        #pragma unroll
        for (int k = 0; k < 15; ++k) {
            w0[k] = conv_w[(2*ic)*15 + k];
            w1[k] = conv_w[(2*ic + 1)*15 + k];
        }
        sA = ws[WS_SC1 + 2*ic];     hA = ws[WS_SH1 + 2*ic];
        sB = ws[WS_SC1 + 2*ic + 1]; hB = ws[WS_SH1 + 2*ic + 1];
        // prologue: chunk 0 x
        #pragma unroll
        for (int r = 0; r < 30; ++r) {
            int t = w*16 - 7 + r;
            xr0[r] = ((unsigned)t < 320u) ? xb[(size_t)t * 64] : 0.f;
        }
    } else {
        spb = sp_b[l];
    }

    // ---- producer body (inlined per phase) ----
    auto produce = [&](int ph, float (&xc)[30], float (&xn)[30]) {
        // 1) prefetch next chunk's x (flies under conv+MFMA)
        if (ph + 1 < 5) {
            const int tsn = (ph + 1)*64 + w*16;
            #pragma unroll
            for (int r = 0; r < 30; ++r) {
                int t = tsn - 7 + r;
                xn[r] = ((unsigned)t < 320u) ? xb[(size_t)t * 64] : 0.f;
            }
        }
        // 2) conv + BN + ReLU + hi/lo split -> own LDS slice (wave-private)
        unsigned short* yh = &ylds[0][0];
        unsigned short* yl = &ylds[1][0];
        #pragma unroll
        for (int j = 0; j < 16; ++j) {
            float a0 = 0.f, a1 = 0.f;
            #pragma unroll
            for (int k = 0; k < 15; ++k) {
                a0 = fmaf(xc[j + k], w0[k], a0);
                a1 = fmaf(xc[j + k], w1[k], a1);
            }
            float y0 = fmaxf(fmaf(a0, sA, hA), 0.f);
            float y1 = fmaxf(fmaf(a1, sB, hB), 0.f);
            int tt = w*16 + j;
            unsigned off = (unsigned)(tt*256) + (((unsigned)(ic*4)) ^ ((unsigned)((tt & 7) << 4)));
            unsigned short y0h = f2bf(y0), y1h = f2bf(y1);
            unsigned short y0l = f2bf(y0 - bf2f(y0h)), y1l = f2bf(y1 - bf2f(y1h));
            *(unsigned*)((char*)yh + off) = (unsigned)y0h | ((unsigned)y1h << 16);
            *(unsigned*)((char*)yl + off) = (unsigned)y0l | ((unsigned)y1l << 16);
        }
        asm volatile("s_waitcnt lgkmcnt(0)" ::: "memory");
        __builtin_amdgcn_sched_barrier(0);

        // 3) MFMA: this wave's 16 t-cols x all 64 h, bf16x4 -> cur LDS
        const int tl = w*16 + (l & 15);    // chunk-local t
        const int kg = l >> 4;
        short8b Bh[4], Bl[4];
        const unsigned tswz = (unsigned)((tl & 7) << 4);
        #pragma unroll
        for (int ks = 0; ks < 4; ++ks) {
            unsigned off = (unsigned)(tl*256) + (((unsigned)(ks*64 + kg*16)) ^ tswz);
            Bh[ks] = *(const short8b*)((const char*)yh + off);
            Bl[ks] = *(const short8b*)((const char*)yl + off);
        }
        const int ha = l & 15;
        float* cbuf = &curl[ph & 1][0];
        #pragma unroll
        for (int mt = 0; mt < 4; ++mt) {
            const unsigned short* ap = wsh + (mt*16 + ha)*128;
            const unsigned short* lp = wsl + (mt*16 + ha)*128;
            f32x4 acc = {0.f, 0.f, 0.f, 0.f};
            #pragma unroll
            for (int ks = 0; ks < 4; ++ks) {
                short8b Ah = *(const short8b*)(ap + ks*32 + kg*8);
                short8b Al = *(const short8b*)(lp + ks*32 + kg*8);
                acc = __builtin_amdgcn_mfma_f32_16x16x32_bf16(Ah, Bh[ks], acc, 0, 0, 0);
                acc = __builtin_amdgcn_mfma_f32_16x16x32_bf16(Ah, Bl[ks], acc, 0, 0, 0);
                acc = __builtin_amdgcn_mfma_f32_16x16x32_bf16(Al, Bh[ks], acc, 0, 0, 0);
                acc = __builtin_amdgcn_mfma_f32_16x16x32_bf16(Al, Bl[ks], acc, 0, 0, 0);
            }
            #pragma unroll
            for (int r = 0; r < 4; ++r)
                cbuf[cidx(tl, mt*16 + kg*4 + r)] = acc[r];
        }
    };

    #pragma unroll
    for (int ph = 0; ph < 6; ++ph) {
        if (wid < 4) {
            if (ph < 5) {
                if ((ph & 1) == 0) produce(ph, xr0, xr1);
                else               produce(ph, xr1, xr0);
            }
        } else {
            if (ph >= 1) {                 // scan chunk ph-1
                const int ck = ph - 1;
                const float* cbuf = &curl[ck & 1][0];
                float sE_lo = 0.f, sE_hi = 0.f;
                #pragma unroll
                for (int gq = 0; gq < 4; ++gq) {
                    float v[16];
                    #pragma unroll
                    for (int q = 0; q < 16; ++q) {
                        int t = gq*16 + q;
                        v[q] = cbuf[cidx(t, l)];
                    }
                    float slo = 0.f, shi = 0.f;
                    #pragma unroll
                    for (int q = 0; q < 16; ++q) {
                        float c = v[q] + spb;
                        mf = fmaf(0.5f, mf, c);
                        bool sf = (mf - 0.5f) >= 0.f;
                        ms = fmaf(0.9f, ms, c);
                        bool ss = (ms - 1.0f) >= 0.f;
                        mf = sf ? 0.f : mf;
                        ms = ss ? 0.f : ms;
                        rlo = fmaf(0.9f, rlo, sf ? 1.f : 0.f);
                        rhi = fmaf(0.9f, rhi, ss ? 1.f : 0.f);
                        slo += rlo; shi += rhi;
                    }
                    if ((gq & 1) == 0) {
                        sE_lo = slo; sE_hi = shi;
                    } else {
                        int wdx = ck*2 + (gq >> 1);
                        Wb[wdx*128 + l]      = slo - sE_lo;
                        Wb[wdx*128 + 64 + l] = shi - sE_hi;
                    }
                }
            }
        }
        __syncthreads();
    }
}

// ---------------- kernel C: classifier epilogue, one block per b ----------------
__global__ void epilogue_kernel(
    const float* __restrict__ tda,    const float* __restrict__ li_b,
    const float* __restrict__ tda_b1, const float* __restrict__ tda_b2,
    const float* __restrict__ cls_b1, const float* __restrict__ cls_w2,
    const float* __restrict__ cls_b2, const float* __restrict__ ws,
    const float* __restrict__ W,      float* __restrict__ out)
{
    __shared__ float Wl[1280];
    __shared__ float t1[64], tf[32], dp[640], h1[128];
    const int b = blockIdx.x, tid = threadIdx.x;

    for (int i = tid; i < 1280; i += NT)
        Wl[i] = W[(size_t)b*1280 + i];
    __syncthreads();

    const float* __restrict__ liwT = ws + WS_LIWT;
    const float* __restrict__ tw1T = ws + WS_TW1T;
    const float* __restrict__ tw2T = ws + WS_TW2T;
    const float* __restrict__ cw1T = ws + WS_CW1T;
    const float* tdab = tda + b*150;

    if (tid < 64) {                     // tda layer 1
        float acc = tda_b1[tid];
        for (int i2 = 0; i2 < 150; ++i2)
            acc = fmaf(tdab[i2], tw1T[i2*64 + tid], acc);
        t1[tid] = fmaxf(acc, 0.f);
    }
    __syncthreads();
    if (tid < 32) {                     // tda layer 2
        float acc = tda_b2[tid];
        #pragma unroll 8
        for (int j = 0; j < 64; ++j)
            acc = fmaf(t1[j], tw2T[j*32 + tid], acc);
        tf[tid] = fmaxf(acc, 0.f);
    }
    // dp_feat = (1/16) * (li_w @ W + li_b * Wg)
    {
        int o = tid & 63;
        for (int w = tid >> 6; w < 10; w += 4) {
            float acc = li_b[o] * ws[WS_WG + w];
            #pragma unroll 4
            for (int j = 0; j < 128; ++j)
                acc = fmaf(Wl[w*128 + j], liwT[j*64 + o], acc);
            dp[w*64 + o] = 0.0625f * acc;
        }
    }
    __syncthreads();
    if (tid < 128) {                    // classifier layer 1 + BN2 + ReLU
        float acc = cls_b1[tid];
        for (int j = 0; j < 640; ++j)
            acc = fmaf(dp[j], cw1T[j*128 + tid], acc);
        #pragma unroll 4
        for (int j = 0; j < 32; ++j)
            acc = fmaf(tf[j], cw1T[(640 + j)*128 + tid], acc);
        float s2 = ws[WS_SC2 + tid], sh2 = ws[WS_SH2 + tid];
        h1[tid] = fmaxf(fmaf(acc, s2, sh2), 0.f);
    }
    __syncthreads();
    if (tid < 4) {                      // classifier layer 2
        float acc = cls_b2[tid];
        for (int c = 0; c < 128; ++c)
            acc = fmaf(h1[c], cls_w2[tid*128 + c], acc);
        out[b*4 + tid] = acc;
    }
}

extern "C" void kernel_launch(void* const* d_in, const int* in_sizes, int n_in,
                              void* d_out, int out_size, void* d_ws, size_t ws_size,
                              hipStream_t stream) {
    const float* x      = (const float*)d_in[0];
    const float* tda    = (const float*)d_in[1];
    const float* conv_w = (const float*)d_in[2];
    const float* conv_b = (const float*)d_in[3];
    const float* bn1_g  = (const float*)d_in[4];
    const float* bn1_b  = (const float*)d_in[5];
    const float* bn1_m  = (const float*)d_in[6];
    const float* bn1_v  = (const float*)d_in[7];
    const float* sp_w   = (const float*)d_in[8];
    const float* sp_b   = (const float*)d_in[9];
    const float* li_w   = (const float*)d_in[10];
    const float* li_b   = (const float*)d_in[11];
    const float* tda_w1 = (const float*)d_in[12];
    const float* tda_b1 = (const float*)d_in[13];
    const float* tda_w2 = (const float*)d_in[14];
    const float* tda_b2 = (const float*)d_in[15];
    const float* cls_w1 = (const float*)d_in[16];
    const float* cls_b1 = (const float*)d_in[17];
    const float* bn2_g  = (const float*)d_in[18];
    const float* bn2_b  = (const float*)d_in[19];
    const float* bn2_m  = (const float*)d_in[20];
    const float* bn2_v  = (const float*)d_in[21];
    const float* cls_w2 = (const float*)d_in[22];
    const float* cls_b2 = (const float*)d_in[23];
    float* ws  = (float*)d_ws;
    float* out = (float*)d_out;

    const int B = in_sizes[0] / (320 * 64);   // 2048

    prep_kernel<<<(WS_TOTAL + 1 + NT - 1)/NT, NT, 0, stream>>>(
        conv_b, bn1_g, bn1_b, bn1_m, bn1_v, sp_w,
        li_w, tda_w1, tda_w2, cls_w1,
        bn2_g, bn2_b, bn2_m, bn2_v, ws);

    fused_kernel<<<B, FNT, 0, stream>>>(
        x, conv_w, sp_b, ws, ws + WS_WBASE);

    epilogue_kernel<<<B, NT, 0, stream>>>(
        tda, li_b, tda_b1, tda_b2, cls_b1, cls_w2, cls_b2,
        ws, ws + WS_WBASE, out);
}